// Round 1
// baseline (1142.198 us; speedup 1.0000x reference)
//
#include <hip/hip_runtime.h>

#define BB 64
#define TT 1024
#define HH 1024
#define II 8
#define OO 8
#define RRK 4
#define NOISE_STD 0.05f
#define ALPHA 0.2f

// DPP-based add: acc + dpp_perm(src). VALU pipe (NOT ds_bpermute like __shfl).
template<int CTRL, int RM>
__device__ __forceinline__ float dpp_add(float acc, float src) {
    int s = __builtin_amdgcn_update_dpp(0, __float_as_int(src), CTRL, RM, 0xF, true);
    return acc + __int_as_float(s);
}

// Full wave64 sum; result valid on lane 63.
__device__ __forceinline__ float wave_sum(float x) {
    x = dpp_add<0xB1, 0xF>(x, x);   // quad_perm [1,0,3,2]  (xor 1)
    x = dpp_add<0x4E, 0xF>(x, x);   // quad_perm [2,3,0,1]  (xor 2)
    x = dpp_add<0x141, 0xF>(x, x);  // row_half_mirror      (xor within 8)
    x = dpp_add<0x140, 0xF>(x, x);  // row_mirror           (within 16)
    x = dpp_add<0x142, 0xA>(x, x);  // row_bcast:15 -> rows 1,3
    x = dpp_add<0x143, 0xC>(x, x);  // row_bcast:31 -> rows 2,3
    return x;
}

// tanh(x) = 1 - 2/(1 + e^{2x}); argument passed as 2x.
__device__ __forceinline__ float tanh_from_2x(float two_x) {
    float e = __expf(two_x);
    float r = __builtin_amdgcn_rcpf(e + 1.0f);
    return fmaf(-2.0f, r, 1.0f);
}

__global__ __launch_bounds__(256, 1)
void rnn_seq_kernel(const float* __restrict__ x, const float* __restrict__ noise,
                    const float* __restrict__ wi, const float* __restrict__ si,
                    const float* __restrict__ mM, const float* __restrict__ nM,
                    const float* __restrict__ bv, const float* __restrict__ wo,
                    const float* __restrict__ so, const float* __restrict__ h0,
                    float* __restrict__ out) {
    __shared__ __align__(16) float lds_x[TT * II];   // 32 KB: x[b] staged once
    __shared__ __align__(16) float red[4][4][16];    // ring[4] x wave[4] x {v[0:4], out[4:12]}

    const int tid  = threadIdx.x;
    const int b    = blockIdx.x;
    const int wave = tid >> 6;
    const int lane = tid & 63;
    const int e0   = tid << 2;                        // first owned h index (4 consecutive)

    // ---- stage x[b] into LDS (coalesced float4) ----
    {
        const float4* src = (const float4*)(x + (size_t)b * (TT * II));
        float4* dst = (float4*)lds_x;
        #pragma unroll
        for (int k = 0; k < 8; ++k)
            dst[k * 256 + tid] = src[k * 256 + tid];
    }

    // ---- fold constants into registers ----
    float wia[II][4];                                 // ALPHA * si[i] * wi[i][h_e]
    #pragma unroll
    for (int i = 0; i < II; ++i) {
        const float s  = ALPHA * si[i];
        const float4 w = *(const float4*)(wi + i * HH + e0);
        wia[i][0] = w.x * s; wia[i][1] = w.y * s; wia[i][2] = w.z * s; wia[i][3] = w.w * s;
    }
    float ma[4][RRK], nr[4][RRK];
    #pragma unroll
    for (int e = 0; e < 4; ++e) {
        const float4 m4 = *(const float4*)(mM + (e0 + e) * RRK);
        const float4 n4 = *(const float4*)(nM + (e0 + e) * RRK);
        const float cs = ALPHA / (float)HH;           // fold ALPHA/H into m
        ma[e][0] = m4.x * cs; ma[e][1] = m4.y * cs; ma[e][2] = m4.z * cs; ma[e][3] = m4.w * cs;
        nr[e][0] = n4.x; nr[e][1] = n4.y; nr[e][2] = n4.z; nr[e][3] = n4.w;
    }
    float woa[4][OO];                                 // wo[h_e][o] * so[o]
    {
        float so8[OO];
        #pragma unroll
        for (int o = 0; o < OO; ++o) so8[o] = so[o];
        #pragma unroll
        for (int e = 0; e < 4; ++e) {
            const float4 a4 = *(const float4*)(wo + (e0 + e) * OO);
            const float4 b4 = *(const float4*)(wo + (e0 + e) * OO + 4);
            woa[e][0] = a4.x * so8[0]; woa[e][1] = a4.y * so8[1];
            woa[e][2] = a4.z * so8[2]; woa[e][3] = a4.w * so8[3];
            woa[e][4] = b4.x * so8[4]; woa[e][5] = b4.y * so8[5];
            woa[e][6] = b4.z * so8[6]; woa[e][7] = b4.w * so8[7];
        }
    }
    float tb2[4], h[4], r[4];
    {
        const float4 b4 = *(const float4*)(bv + e0);
        tb2[0] = 2.f * b4.x; tb2[1] = 2.f * b4.y; tb2[2] = 2.f * b4.z; tb2[3] = 2.f * b4.w;
        const float4 h4 = *(const float4*)(h0 + e0);
        h[0] = h4.x; h[1] = h4.y; h[2] = h4.z; h[3] = h4.w;
        #pragma unroll
        for (int e = 0; e < 4; ++e) r[e] = tanh_from_2x(2.f * h[e]);  // r_init = tanh(h0), no bias
    }

    // ---- noise prefetch pipeline (depth 4) ----
    const float* nzp = noise + (size_t)b * (TT * HH) + e0;
    float4 nzb[4];
    #pragma unroll
    for (int j = 0; j < 4; ++j) nzb[j] = *(const float4*)(nzp + (size_t)j * HH);

    float* outb = out + b * (TT * OO);

    __syncthreads();

    for (int t0 = 0; t0 < TT; t0 += 4) {
        #pragma unroll
        for (int j = 0; j < 4; ++j) {
            const int t = t0 + j;                     // ring slot == j (t0 % 4 == 0)

            // 1. v partials: v_q = sum_h r[h]*n[h][q]
            float vp[RRK];
            #pragma unroll
            for (int q = 0; q < RRK; ++q)
                vp[q] = fmaf(r[0], nr[0][q], fmaf(r[1], nr[1][q], fmaf(r[2], nr[2][q], r[3] * nr[3][q])));
            #pragma unroll
            for (int q = 0; q < RRK; ++q) vp[q] = wave_sum(vp[q]);
            if (lane == 63)
                *(float4*)&red[j][wave][0] = make_float4(vp[0], vp[1], vp[2], vp[3]);

            // 2. alpha*u from x in LDS (wave-uniform broadcast reads)
            const float4 xv0 = *(const float4*)&lds_x[t * II];
            const float4 xv1 = *(const float4*)&lds_x[t * II + 4];
            float au[4];
            #pragma unroll
            for (int e = 0; e < 4; ++e) {
                float a = xv0.x * wia[0][e];
                a = fmaf(xv0.y, wia[1][e], a);
                a = fmaf(xv0.z, wia[2][e], a);
                a = fmaf(xv0.w, wia[3][e], a);
                a = fmaf(xv1.x, wia[4][e], a);
                a = fmaf(xv1.y, wia[5][e], a);
                a = fmaf(xv1.z, wia[6][e], a);
                au[e] = fmaf(xv1.w, wia[7][e], a);
            }

            __syncthreads();   // the one barrier per step

            // 3. cross-wave v totals (broadcast LDS reads)
            const float4 s0 = *(const float4*)&red[j][0][0];
            const float4 s1 = *(const float4*)&red[j][1][0];
            const float4 s2 = *(const float4*)&red[j][2][0];
            const float4 s3 = *(const float4*)&red[j][3][0];
            const float v0 = (s0.x + s1.x) + (s2.x + s3.x);
            const float v1 = (s0.y + s1.y) + (s2.y + s3.y);
            const float v2 = (s0.z + s1.z) + (s2.z + s3.z);
            const float v3 = (s0.w + s1.w) + (s2.w + s3.w);

            // 4. h update: h = 0.8h + alpha*(rec+u) + 0.05*nz
            const float nzv[4] = {nzb[j].x, nzb[j].y, nzb[j].z, nzb[j].w};
            #pragma unroll
            for (int e = 0; e < 4; ++e) {
                float acc = au[e];
                acc = fmaf(v0, ma[e][0], acc);
                acc = fmaf(v1, ma[e][1], acc);
                acc = fmaf(v2, ma[e][2], acc);
                acc = fmaf(v3, ma[e][3], acc);
                h[e] = fmaf(NOISE_STD, nzv[e], fmaf(1.0f - ALPHA, h[e], acc));
            }

            // 5. out partials: out_o = sum_h h[h]*woa[h][o]
            float op[OO];
            #pragma unroll
            for (int o = 0; o < OO; ++o)
                op[o] = fmaf(h[0], woa[0][o], fmaf(h[1], woa[1][o], fmaf(h[2], woa[2][o], h[3] * woa[3][o])));
            #pragma unroll
            for (int o = 0; o < OO; ++o) op[o] = wave_sum(op[o]);
            if (lane == 63) {
                *(float4*)&red[j][wave][4] = make_float4(op[0], op[1], op[2], op[3]);
                *(float4*)&red[j][wave][8] = make_float4(op[4], op[5], op[6], op[7]);
            }

            // 6. finish + store out for step t-1 (its parts are pre-barrier_t)
            if (t > 0 && tid < OO) {
                const int pp = (t - 1) & 3;
                const float s = (red[pp][0][4 + tid] + red[pp][1][4 + tid]) +
                                (red[pp][2][4 + tid] + red[pp][3][4 + tid]);
                outb[(t - 1) * OO + tid] = s;
            }

            // 7. r = tanh(h + b) for next step
            #pragma unroll
            for (int e = 0; e < 4; ++e)
                r[e] = tanh_from_2x(fmaf(2.0f, h[e], tb2[e]));

            // 8. prefetch noise for t+4 (wrap harmlessly at the tail)
            int tn = t + 4; if (tn >= TT) tn = 0;
            nzb[j] = *(const float4*)(nzp + (size_t)tn * HH);
        }
    }

    __syncthreads();
    if (tid < OO) {
        const int pp = (TT - 1) & 3;
        const float s = (red[pp][0][4 + tid] + red[pp][1][4 + tid]) +
                        (red[pp][2][4 + tid] + red[pp][3][4 + tid]);
        outb[(TT - 1) * OO + tid] = s;
    }
}

extern "C" void kernel_launch(void* const* d_in, const int* in_sizes, int n_in,
                              void* d_out, int out_size, void* d_ws, size_t ws_size,
                              hipStream_t stream) {
    const float* x     = (const float*)d_in[0];
    const float* noise = (const float*)d_in[1];
    const float* wi    = (const float*)d_in[2];
    const float* si    = (const float*)d_in[3];
    const float* mM    = (const float*)d_in[4];
    const float* nM    = (const float*)d_in[5];
    const float* bv    = (const float*)d_in[6];
    const float* wo    = (const float*)d_in[7];
    const float* so    = (const float*)d_in[8];
    const float* h0    = (const float*)d_in[9];
    float* out = (float*)d_out;

    rnn_seq_kernel<<<dim3(BB), dim3(256), 0, stream>>>(
        x, noise, wi, si, mM, nM, bv, wo, so, h0, out);
}

// Round 2
// 1054.731 us; speedup vs baseline: 1.0829x; 1.0829x over previous
//
#include <hip/hip_runtime.h>

#define BB 64
#define TT 1024
#define HH 1024
#define II 8
#define OO 8
#define RRK 4
#define NOISE_STD 0.05f
#define ALPHA 0.2f

// DPP-based add: acc + dpp_perm(src). VALU pipe (NOT ds_bpermute like __shfl).
template<int CTRL, int RM>
__device__ __forceinline__ float dpp_add(float acc, float src) {
    int s = __builtin_amdgcn_update_dpp(0, __float_as_int(src), CTRL, RM, 0xF, true);
    return acc + __int_as_float(s);
}

// Full wave64 sum; result valid on lane 63.
__device__ __forceinline__ float wave_sum(float x) {
    x = dpp_add<0xB1, 0xF>(x, x);   // xor 1
    x = dpp_add<0x4E, 0xF>(x, x);   // xor 2
    x = dpp_add<0x141, 0xF>(x, x);  // row_half_mirror
    x = dpp_add<0x140, 0xF>(x, x);  // row_mirror
    x = dpp_add<0x142, 0xA>(x, x);  // row_bcast:15
    x = dpp_add<0x143, 0xC>(x, x);  // row_bcast:31
    return x;
}

// tanh(x) = 1 - 2/(1 + e^{2x}); argument passed as 2x.
__device__ __forceinline__ float tanh_from_2x(float two_x) {
    float e = __expf(two_x);
    float r = __builtin_amdgcn_rcpf(e + 1.0f);
    return fmaf(-2.0f, r, 1.0f);
}

// Barrier WITHOUT the vmcnt(0) drain that __syncthreads() forces.
// Waits only LDS ops (our red[] writes), leaves global prefetches in flight.
__device__ __forceinline__ void block_sync_lds() {
    asm volatile("s_waitcnt lgkmcnt(0)\n\ts_barrier" ::: "memory");
}

__global__ __launch_bounds__(256, 1)
void rnn_seq_kernel(const float* __restrict__ x, const float* __restrict__ noise,
                    const float* __restrict__ wi, const float* __restrict__ si,
                    const float* __restrict__ mM, const float* __restrict__ nM,
                    const float* __restrict__ bv, const float* __restrict__ wo,
                    const float* __restrict__ so, const float* __restrict__ h0,
                    float* __restrict__ out) {
    __shared__ __align__(16) float lds_x[TT * II];     // 32 KB: x[b] staged once
    __shared__ __align__(16) float lds_out[TT * OO];   // 32 KB: out sink (no per-step global stores)
    __shared__ __align__(16) float red[4][4][16];      // ring[4] x wave[4] x {v[0:4], out[4:12]}

    const int tid  = threadIdx.x;
    const int b    = blockIdx.x;
    const int wave = tid >> 6;
    const int lane = tid & 63;
    const int e0   = tid << 2;                         // first owned h index (4 consecutive)

    // ---- stage x[b] into LDS (coalesced float4) ----
    {
        const float4* src = (const float4*)(x + (size_t)b * (TT * II));
        float4* dst = (float4*)lds_x;
        #pragma unroll
        for (int k = 0; k < 8; ++k)
            dst[k * 256 + tid] = src[k * 256 + tid];
    }

    // ---- fold constants into registers ----
    float wia[II][4];                                  // ALPHA * si[i] * wi[i][h_e]
    #pragma unroll
    for (int i = 0; i < II; ++i) {
        const float s  = ALPHA * si[i];
        const float4 w = *(const float4*)(wi + i * HH + e0);
        wia[i][0] = w.x * s; wia[i][1] = w.y * s; wia[i][2] = w.z * s; wia[i][3] = w.w * s;
    }
    float ma[4][RRK], nr[4][RRK];
    #pragma unroll
    for (int e = 0; e < 4; ++e) {
        const float4 m4 = *(const float4*)(mM + (e0 + e) * RRK);
        const float4 n4 = *(const float4*)(nM + (e0 + e) * RRK);
        const float cs = ALPHA / (float)HH;            // fold ALPHA/H into m
        ma[e][0] = m4.x * cs; ma[e][1] = m4.y * cs; ma[e][2] = m4.z * cs; ma[e][3] = m4.w * cs;
        nr[e][0] = n4.x; nr[e][1] = n4.y; nr[e][2] = n4.z; nr[e][3] = n4.w;
    }
    float woa[4][OO];                                  // wo[h_e][o] * so[o]
    {
        float so8[OO];
        #pragma unroll
        for (int o = 0; o < OO; ++o) so8[o] = so[o];
        #pragma unroll
        for (int e = 0; e < 4; ++e) {
            const float4 a4 = *(const float4*)(wo + (e0 + e) * OO);
            const float4 b4 = *(const float4*)(wo + (e0 + e) * OO + 4);
            woa[e][0] = a4.x * so8[0]; woa[e][1] = a4.y * so8[1];
            woa[e][2] = a4.z * so8[2]; woa[e][3] = a4.w * so8[3];
            woa[e][4] = b4.x * so8[4]; woa[e][5] = b4.y * so8[5];
            woa[e][6] = b4.z * so8[6]; woa[e][7] = b4.w * so8[7];
        }
    }
    float tb2[4], h[4], r[4];
    {
        const float4 b4 = *(const float4*)(bv + e0);
        tb2[0] = 2.f * b4.x; tb2[1] = 2.f * b4.y; tb2[2] = 2.f * b4.z; tb2[3] = 2.f * b4.w;
        const float4 h4 = *(const float4*)(h0 + e0);
        h[0] = h4.x; h[1] = h4.y; h[2] = h4.z; h[3] = h4.w;
        #pragma unroll
        for (int e = 0; e < 4; ++e) r[e] = tanh_from_2x(2.f * h[e]);  // r_init = tanh(h0)
    }

    // ---- noise prefetch pipeline (depth 4) ----
    const float* nzp = noise + (size_t)b * (TT * HH) + e0;
    float4 nzb[4];
    #pragma unroll
    for (int j = 0; j < 4; ++j) nzb[j] = *(const float4*)(nzp + (size_t)j * HH);

    __syncthreads();   // once: lds_x visible (full drain is fine here)

    // x pipeline: xq holds x[t] for the upcoming step
    float4 xq0 = *(const float4*)&lds_x[0];
    float4 xq1 = *(const float4*)&lds_x[4];

    for (int t0 = 0; t0 < TT; t0 += 4) {
        #pragma unroll
        for (int j = 0; j < 4; ++j) {
            const int t = t0 + j;                      // ring slot == j

            // A. v partials from r
            float vp[RRK];
            #pragma unroll
            for (int q = 0; q < RRK; ++q)
                vp[q] = fmaf(r[0], nr[0][q], fmaf(r[1], nr[1][q], fmaf(r[2], nr[2][q], r[3] * nr[3][q])));
            #pragma unroll
            for (int q = 0; q < RRK; ++q) vp[q] = wave_sum(vp[q]);
            if (lane == 63)
                *(float4*)&red[j][wave][0] = make_float4(vp[0], vp[1], vp[2], vp[3]);

            // B. LDS-only barrier — noise prefetches stay in flight
            block_sync_lds();

            // C. issue red.v reads immediately (latency overlapped by D/E below)
            const float4 s0 = *(const float4*)&red[j][0][0];
            const float4 s1 = *(const float4*)&red[j][1][0];
            const float4 s2 = *(const float4*)&red[j][2][0];
            const float4 s3 = *(const float4*)&red[j][3][0];

            // D. alpha*u_t from xq regs, then reload xq for t+1
            float au[4];
            #pragma unroll
            for (int e = 0; e < 4; ++e) {
                float a = xq0.x * wia[0][e];
                a = fmaf(xq0.y, wia[1][e], a);
                a = fmaf(xq0.z, wia[2][e], a);
                a = fmaf(xq0.w, wia[3][e], a);
                a = fmaf(xq1.x, wia[4][e], a);
                a = fmaf(xq1.y, wia[5][e], a);
                a = fmaf(xq1.z, wia[6][e], a);
                au[e] = fmaf(xq1.w, wia[7][e], a);
            }
            {
                const int tn = (t + 1 < TT) ? t + 1 : TT - 1;
                xq0 = *(const float4*)&lds_x[tn * II];
                xq1 = *(const float4*)&lds_x[tn * II + 4];
            }

            // E. out partials for step t-1 (uses h entering this step) — more overlap work
            if (t > 0) {
                float op[OO];
                #pragma unroll
                for (int o = 0; o < OO; ++o)
                    op[o] = fmaf(h[0], woa[0][o], fmaf(h[1], woa[1][o], fmaf(h[2], woa[2][o], h[3] * woa[3][o])));
                #pragma unroll
                for (int o = 0; o < OO; ++o) op[o] = wave_sum(op[o]);
                if (lane == 63) {
                    *(float4*)&red[(t - 1) & 3][wave][4] = make_float4(op[0], op[1], op[2], op[3]);
                    *(float4*)&red[(t - 1) & 3][wave][8] = make_float4(op[4], op[5], op[6], op[7]);
                }
            }

            // F. v totals
            const float v0 = (s0.x + s1.x) + (s2.x + s3.x);
            const float v1 = (s0.y + s1.y) + (s2.y + s3.y);
            const float v2 = (s0.z + s1.z) + (s2.z + s3.z);
            const float v3 = (s0.w + s1.w) + (s2.w + s3.w);

            // G. h update
            const float nzv[4] = {nzb[j].x, nzb[j].y, nzb[j].z, nzb[j].w};
            #pragma unroll
            for (int e = 0; e < 4; ++e) {
                float acc = au[e];
                acc = fmaf(v0, ma[e][0], acc);
                acc = fmaf(v1, ma[e][1], acc);
                acc = fmaf(v2, ma[e][2], acc);
                acc = fmaf(v3, ma[e][3], acc);
                h[e] = fmaf(NOISE_STD, nzv[e], fmaf(1.0f - ALPHA, h[e], acc));
            }

            // H. prefetch noise for t+4
            {
                int tn = t + 4; if (tn >= TT) tn = 0;
                nzb[j] = *(const float4*)(nzp + (size_t)tn * HH);
            }

            // I. r = tanh(h + b) — critical path for next step's vp
            #pragma unroll
            for (int e = 0; e < 4; ++e)
                r[e] = tanh_from_2x(fmaf(2.0f, h[e], tb2[e]));

            // J. combine + sink out for step t-2 (partials written at step t-1, visible post-barrier)
            if (t > 1 && tid < OO) {
                const int pp = (t - 2) & 3;
                const float s = (red[pp][0][4 + tid] + red[pp][1][4 + tid]) +
                                (red[pp][2][4 + tid] + red[pp][3][4 + tid]);
                lds_out[(t - 2) * OO + tid] = s;
            }
        }
    }

    // ---- tail: out partials for step TT-1, combine TT-2 and TT-1 ----
    {
        float op[OO];
        #pragma unroll
        for (int o = 0; o < OO; ++o)
            op[o] = fmaf(h[0], woa[0][o], fmaf(h[1], woa[1][o], fmaf(h[2], woa[2][o], h[3] * woa[3][o])));
        #pragma unroll
        for (int o = 0; o < OO; ++o) op[o] = wave_sum(op[o]);
        if (lane == 63) {
            *(float4*)&red[(TT - 1) & 3][wave][4] = make_float4(op[0], op[1], op[2], op[3]);
            *(float4*)&red[(TT - 1) & 3][wave][8] = make_float4(op[4], op[5], op[6], op[7]);
        }
        block_sync_lds();
        if (tid < OO) {
            const int p1 = (TT - 2) & 3;
            const int p2 = (TT - 1) & 3;
            lds_out[(TT - 2) * OO + tid] = (red[p1][0][4 + tid] + red[p1][1][4 + tid]) +
                                           (red[p1][2][4 + tid] + red[p1][3][4 + tid]);
            lds_out[(TT - 1) * OO + tid] = (red[p2][0][4 + tid] + red[p2][1][4 + tid]) +
                                           (red[p2][2][4 + tid] + red[p2][3][4 + tid]);
        }
    }

    __syncthreads();

    // ---- single coalesced out store ----
    {
        float4* dst = (float4*)(out + (size_t)b * (TT * OO));
        const float4* srcv = (const float4*)lds_out;
        #pragma unroll
        for (int k = 0; k < 8; ++k)
            dst[k * 256 + tid] = srcv[k * 256 + tid];
    }
}

extern "C" void kernel_launch(void* const* d_in, const int* in_sizes, int n_in,
                              void* d_out, int out_size, void* d_ws, size_t ws_size,
                              hipStream_t stream) {
    const float* x     = (const float*)d_in[0];
    const float* noise = (const float*)d_in[1];
    const float* wi    = (const float*)d_in[2];
    const float* si    = (const float*)d_in[3];
    const float* mM    = (const float*)d_in[4];
    const float* nM    = (const float*)d_in[5];
    const float* bv    = (const float*)d_in[6];
    const float* wo    = (const float*)d_in[7];
    const float* so    = (const float*)d_in[8];
    const float* h0    = (const float*)d_in[9];
    float* out = (float*)d_out;

    rnn_seq_kernel<<<dim3(BB), dim3(256), 0, stream>>>(
        x, noise, wi, si, mM, nM, bv, wo, so, h0, out);
}

// Round 3
// 848.491 us; speedup vs baseline: 1.3462x; 1.2431x over previous
//
#include <hip/hip_runtime.h>

#define BB 64
#define TT 1024
#define HH 1024
#define II 8
#define OO 8
#define RRK 4
#define NOISE_STD 0.05f
#define ALPHA 0.2f

// DPP-based add: acc + dpp_perm(src). VALU pipe (NOT ds_bpermute like __shfl).
template<int CTRL, int RM>
__device__ __forceinline__ float dpp_add(float acc, float src) {
    int s = __builtin_amdgcn_update_dpp(0, __float_as_int(src), CTRL, RM, 0xF, true);
    return acc + __int_as_float(s);
}

// Full wave64 sum; result valid on lane 63.
__device__ __forceinline__ float wave_sum(float x) {
    x = dpp_add<0xB1, 0xF>(x, x);   // xor 1
    x = dpp_add<0x4E, 0xF>(x, x);   // xor 2
    x = dpp_add<0x141, 0xF>(x, x);  // row_half_mirror
    x = dpp_add<0x140, 0xF>(x, x);  // row_mirror
    x = dpp_add<0x142, 0xA>(x, x);  // row_bcast:15
    x = dpp_add<0x143, 0xC>(x, x);  // row_bcast:31
    return x;
}

// tanh(x) = 1 - 2/(1 + e^{2x}); argument passed as 2x.
__device__ __forceinline__ float tanh_from_2x(float two_x) {
    float e = __expf(two_x);
    float r = __builtin_amdgcn_rcpf(e + 1.0f);
    return fmaf(-2.0f, r, 1.0f);
}

// Barrier WITHOUT the vmcnt(0) drain of __syncthreads(): waits only LDS ops.
__device__ __forceinline__ void block_sync_lds() {
    asm volatile("s_waitcnt lgkmcnt(0)\n\ts_barrier" ::: "memory");
}

// ---------------------------------------------------------------------------
// Pre-kernel: W[row][o] = NOISE_STD * sum_h noise[row,h] * wo[h][o]*so[o]
// row = b*TT + t, 65536 rows. Memory-bound: reads 256 MB on full chip.
// ---------------------------------------------------------------------------
__global__ __launch_bounds__(256)
void prew_kernel(const float* __restrict__ noise, const float* __restrict__ wo,
                 const float* __restrict__ so, float* __restrict__ W) {
    __shared__ __align__(16) float red[4][4][8];   // ring x wave x o

    const int tid  = threadIdx.x;
    const int wave = tid >> 6;
    const int lane = tid & 63;
    const int e0   = tid << 2;                     // h = e0..e0+3

    float woa[4][OO];
    {
        float so8[OO];
        #pragma unroll
        for (int o = 0; o < OO; ++o) so8[o] = so[o] * NOISE_STD;
        #pragma unroll
        for (int e = 0; e < 4; ++e) {
            const float4 a4 = *(const float4*)(wo + (e0 + e) * OO);
            const float4 b4 = *(const float4*)(wo + (e0 + e) * OO + 4);
            woa[e][0] = a4.x * so8[0]; woa[e][1] = a4.y * so8[1];
            woa[e][2] = a4.z * so8[2]; woa[e][3] = a4.w * so8[3];
            woa[e][4] = b4.x * so8[4]; woa[e][5] = b4.y * so8[5];
            woa[e][6] = b4.z * so8[6]; woa[e][7] = b4.w * so8[7];
        }
    }

    const int row0 = blockIdx.x * 32;
    for (int g = 0; g < 8; ++g) {
        #pragma unroll
        for (int j = 0; j < 4; ++j) {
            const int row = row0 + g * 4 + j;
            const float4 nz = *(const float4*)(noise + (size_t)row * HH + e0);
            float op[OO];
            #pragma unroll
            for (int o = 0; o < OO; ++o)
                op[o] = fmaf(nz.x, woa[0][o], fmaf(nz.y, woa[1][o],
                        fmaf(nz.z, woa[2][o], nz.w * woa[3][o])));
            #pragma unroll
            for (int o = 0; o < OO; ++o) op[o] = wave_sum(op[o]);
            if (lane == 63) {
                *(float4*)&red[j][wave][0] = make_float4(op[0], op[1], op[2], op[3]);
                *(float4*)&red[j][wave][4] = make_float4(op[4], op[5], op[6], op[7]);
            }
        }
        block_sync_lds();
        if (tid < 32) {
            const int j = tid >> 3, o = tid & 7;
            const int row = row0 + g * 4 + j;
            W[row * OO + o] = (red[j][0][o] + red[j][1][o]) +
                              (red[j][2][o] + red[j][3][o]);
        }
        block_sync_lds();   // protect red[] reuse by next group
    }
}

// ---------------------------------------------------------------------------
// Main RNN kernel: one block per batch; out via 8-dim y-recurrence.
// ---------------------------------------------------------------------------
__global__ __launch_bounds__(256, 1)
void rnn_seq_kernel(const float* __restrict__ x, const float* __restrict__ noise,
                    const float* __restrict__ wi, const float* __restrict__ si,
                    const float* __restrict__ mM, const float* __restrict__ nM,
                    const float* __restrict__ bv, const float* __restrict__ wo,
                    const float* __restrict__ so, const float* __restrict__ h0,
                    const float* __restrict__ W, float* __restrict__ out) {
    __shared__ __align__(16) float lds_x[TT * II];    // 32 KB
    __shared__ __align__(16) float lds_W[TT * OO];    // 32 KB (sigma-scaled noise@woa)
    __shared__ __align__(16) float lds_out[TT * OO];  // 32 KB
    __shared__ __align__(16) float red[4][4][4];      // ring x wave x q
    __shared__ __align__(16) float redc[4][104];      // preamble scratch (wave-major)
    __shared__ float ambx[104];                       // Am(32) | Bx(64) | y0(8)

    const int tid  = threadIdx.x;
    const int b    = blockIdx.x;
    const int wave = tid >> 6;
    const int lane = tid & 63;
    const int e0   = tid << 2;
    const int oc   = tid & 7;                         // this thread's o-column for y

    // ---- stage x[b] and W[b] into LDS ----
    {
        const float4* sx = (const float4*)(x + (size_t)b * (TT * II));
        const float4* sw = (const float4*)(W + (size_t)b * (TT * OO));
        float4* dx = (float4*)lds_x;
        float4* dw = (float4*)lds_W;
        #pragma unroll
        for (int k = 0; k < 8; ++k) {
            dx[k * 256 + tid] = sx[k * 256 + tid];
            dw[k * 256 + tid] = sw[k * 256 + tid];
        }
    }

    // ---- fold constants into registers ----
    float wia[II][4];                                  // ALPHA*si[i]*wi[i][h_e]
    #pragma unroll
    for (int i = 0; i < II; ++i) {
        const float s  = ALPHA * si[i];
        const float4 w = *(const float4*)(wi + i * HH + e0);
        wia[i][0] = w.x * s; wia[i][1] = w.y * s; wia[i][2] = w.z * s; wia[i][3] = w.w * s;
    }
    float ma[4][RRK], nr[4][RRK];
    #pragma unroll
    for (int e = 0; e < 4; ++e) {
        const float4 m4 = *(const float4*)(mM + (e0 + e) * RRK);
        const float4 n4 = *(const float4*)(nM + (e0 + e) * RRK);
        const float cs = ALPHA / (float)HH;            // fold ALPHA/H into m
        ma[e][0] = m4.x * cs; ma[e][1] = m4.y * cs; ma[e][2] = m4.z * cs; ma[e][3] = m4.w * cs;
        nr[e][0] = n4.x; nr[e][1] = n4.y; nr[e][2] = n4.z; nr[e][3] = n4.w;
    }
    float woa[4][OO];                                  // wo[h_e][o]*so[o]  (preamble only)
    {
        float so8[OO];
        #pragma unroll
        for (int o = 0; o < OO; ++o) so8[o] = so[o];
        #pragma unroll
        for (int e = 0; e < 4; ++e) {
            const float4 a4 = *(const float4*)(wo + (e0 + e) * OO);
            const float4 b4 = *(const float4*)(wo + (e0 + e) * OO + 4);
            woa[e][0] = a4.x * so8[0]; woa[e][1] = a4.y * so8[1];
            woa[e][2] = a4.z * so8[2]; woa[e][3] = a4.w * so8[3];
            woa[e][4] = b4.x * so8[4]; woa[e][5] = b4.y * so8[5];
            woa[e][6] = b4.z * so8[6]; woa[e][7] = b4.w * so8[7];
        }
    }
    float tb2[4], h[4], r[4];
    {
        const float4 b4 = *(const float4*)(bv + e0);
        tb2[0] = 2.f * b4.x; tb2[1] = 2.f * b4.y; tb2[2] = 2.f * b4.z; tb2[3] = 2.f * b4.w;
        const float4 h4 = *(const float4*)(h0 + e0);
        h[0] = h4.x; h[1] = h4.y; h[2] = h4.z; h[3] = h4.w;
        #pragma unroll
        for (int e = 0; e < 4; ++e) r[e] = tanh_from_2x(2.f * h[e]);
    }

    // ---- preamble: reduce Am (4x8), Bx (8x8), y0 (8) from register-folded weights ----
    // outputs k: [0,32) Am[q=k>>3][o=k&7]; [32,96) Bx[i=(k-32)>>3][o]; [96,104) y0[o]
    #pragma unroll
    for (int kg = 0; kg < 26; ++kg) {
        float p[4];
        #pragma unroll
        for (int u = 0; u < 4; ++u) {
            const int k = kg * 4 + u;
            float s;
            if (k < 32) {
                const int q = k >> 3, o = k & 7;
                s = fmaf(ma[0][q], woa[0][o], fmaf(ma[1][q], woa[1][o],
                    fmaf(ma[2][q], woa[2][o], ma[3][q] * woa[3][o])));
            } else if (k < 96) {
                const int i = (k - 32) >> 3, o = k & 7;
                s = fmaf(wia[i][0], woa[0][o], fmaf(wia[i][1], woa[1][o],
                    fmaf(wia[i][2], woa[2][o], wia[i][3] * woa[3][o])));
            } else {
                const int o = k - 96;
                s = fmaf(h[0], woa[0][o], fmaf(h[1], woa[1][o],
                    fmaf(h[2], woa[2][o], h[3] * woa[3][o])));
            }
            p[u] = wave_sum(s);
        }
        if (lane == 63)
            *(float4*)&redc[wave][kg * 4] = make_float4(p[0], p[1], p[2], p[3]);
    }
    block_sync_lds();
    if (tid < 104)
        ambx[tid] = (redc[0][tid] + redc[1][tid]) + (redc[2][tid] + redc[3][tid]);
    __syncthreads();   // also covers lds_x / lds_W staging visibility

    float Amr[RRK], Bxr[II], y;
    #pragma unroll
    for (int q = 0; q < RRK; ++q) Amr[q] = ambx[q * 8 + oc];
    #pragma unroll
    for (int i = 0; i < II; ++i) Bxr[i] = ambx[32 + i * 8 + oc];
    y = ambx[96 + oc];

    // ---- pipelined operand state for t=0 ----
    const float* nzp = noise + (size_t)b * (TT * HH) + e0;
    float4 nzb[4];
    #pragma unroll
    for (int j = 0; j < 4; ++j) nzb[j] = *(const float4*)(nzp + (size_t)j * HH);

    float4 xqc0 = *(const float4*)&lds_x[0];
    float4 xqc1 = *(const float4*)&lds_x[4];
    float  wqc  = lds_W[oc];

    for (int t0 = 0; t0 < TT; t0 += 4) {
        #pragma unroll
        for (int j = 0; j < 4; ++j) {
            const int t = t0 + j;

            // A. issue next-step operand loads early (latency hidden by B-D)
            const int tn = (t + 1 < TT) ? t + 1 : TT - 1;
            const float4 xqn0 = *(const float4*)&lds_x[tn * II];
            const float4 xqn1 = *(const float4*)&lds_x[tn * II + 4];
            const float  wqn  = lds_W[tn * OO + oc];

            // B. v partials from r + in-wave reduction
            float vp[RRK];
            #pragma unroll
            for (int q = 0; q < RRK; ++q)
                vp[q] = fmaf(r[0], nr[0][q], fmaf(r[1], nr[1][q],
                        fmaf(r[2], nr[2][q], r[3] * nr[3][q])));
            #pragma unroll
            for (int q = 0; q < RRK; ++q) vp[q] = wave_sum(vp[q]);
            if (lane == 63)
                *(float4*)&red[j][wave][0] = make_float4(vp[0], vp[1], vp[2], vp[3]);

            // C. ybase = x_t·Bx[.][oc] + W_t[oc]  (v-independent part of y)
            float ybase = fmaf(xqc0.x, Bxr[0], wqc);
            ybase = fmaf(xqc0.y, Bxr[1], ybase);
            ybase = fmaf(xqc0.z, Bxr[2], ybase);
            ybase = fmaf(xqc0.w, Bxr[3], ybase);
            ybase = fmaf(xqc1.x, Bxr[4], ybase);
            ybase = fmaf(xqc1.y, Bxr[5], ybase);
            ybase = fmaf(xqc1.z, Bxr[6], ybase);
            ybase = fmaf(xqc1.w, Bxr[7], ybase);

            // D. alpha*u_t
            float au[4];
            #pragma unroll
            for (int e = 0; e < 4; ++e) {
                float a = xqc0.x * wia[0][e];
                a = fmaf(xqc0.y, wia[1][e], a);
                a = fmaf(xqc0.z, wia[2][e], a);
                a = fmaf(xqc0.w, wia[3][e], a);
                a = fmaf(xqc1.x, wia[4][e], a);
                a = fmaf(xqc1.y, wia[5][e], a);
                a = fmaf(xqc1.z, wia[6][e], a);
                au[e] = fmaf(xqc1.w, wia[7][e], a);
            }

            // E. LDS-only barrier (global prefetches stay in flight)
            block_sync_lds();

            // F. cross-wave v totals
            const float4 s0 = *(const float4*)&red[j][0][0];
            const float4 s1 = *(const float4*)&red[j][1][0];
            const float4 s2 = *(const float4*)&red[j][2][0];
            const float4 s3 = *(const float4*)&red[j][3][0];
            const float v0 = (s0.x + s1.x) + (s2.x + s3.x);
            const float v1 = (s0.y + s1.y) + (s2.y + s3.y);
            const float v2 = (s0.z + s1.z) + (s2.z + s3.z);
            const float v3 = (s0.w + s1.w) + (s2.w + s3.w);

            // G. h update
            const float nzv[4] = {nzb[j].x, nzb[j].y, nzb[j].z, nzb[j].w};
            #pragma unroll
            for (int e = 0; e < 4; ++e) {
                float acc = au[e];
                acc = fmaf(v0, ma[e][0], acc);
                acc = fmaf(v1, ma[e][1], acc);
                acc = fmaf(v2, ma[e][2], acc);
                acc = fmaf(v3, ma[e][3], acc);
                h[e] = fmaf(NOISE_STD, nzv[e], fmaf(1.0f - ALPHA, h[e], acc));
            }

            // H. y recurrence (all lanes compute column oc; wave0 tid<8 writes)
            {
                float t4 = fmaf(v0, Amr[0], ybase);
                t4 = fmaf(v1, Amr[1], t4);
                t4 = fmaf(v2, Amr[2], t4);
                t4 = fmaf(v3, Amr[3], t4);
                y = fmaf(1.0f - ALPHA, y, t4);
                if (tid < OO) lds_out[t * OO + tid] = y;
            }

            // I. noise prefetch for t+4
            {
                int tf = t + 4; if (tf >= TT) tf = 0;
                nzb[j] = *(const float4*)(nzp + (size_t)tf * HH);
            }

            // J. r = tanh(h + b) — critical path to next step
            #pragma unroll
            for (int e = 0; e < 4; ++e)
                r[e] = tanh_from_2x(fmaf(2.0f, h[e], tb2[e]));

            // K. advance operand pipeline
            xqc0 = xqn0; xqc1 = xqn1; wqc = wqn;
        }
    }

    __syncthreads();
    {
        float4* dst = (float4*)(out + (size_t)b * (TT * OO));
        const float4* srcv = (const float4*)lds_out;
        #pragma unroll
        for (int k = 0; k < 8; ++k)
            dst[k * 256 + tid] = srcv[k * 256 + tid];
    }
}

extern "C" void kernel_launch(void* const* d_in, const int* in_sizes, int n_in,
                              void* d_out, int out_size, void* d_ws, size_t ws_size,
                              hipStream_t stream) {
    const float* x     = (const float*)d_in[0];
    const float* noise = (const float*)d_in[1];
    const float* wi    = (const float*)d_in[2];
    const float* si    = (const float*)d_in[3];
    const float* mM    = (const float*)d_in[4];
    const float* nM    = (const float*)d_in[5];
    const float* bv    = (const float*)d_in[6];
    const float* wo    = (const float*)d_in[7];
    const float* so    = (const float*)d_in[8];
    const float* h0    = (const float*)d_in[9];
    float* out = (float*)d_out;
    float* W   = (float*)d_ws;   // 65536 x 8 fp32 = 2 MB

    prew_kernel<<<dim3(2048), dim3(256), 0, stream>>>(noise, wo, so, W);
    rnn_seq_kernel<<<dim3(BB), dim3(256), 0, stream>>>(
        x, noise, wi, si, mM, nM, bv, wo, so, h0, W, out);
}